// Round 2
// baseline (151.537 us; speedup 1.0000x reference)
//
#include <hip/hip_runtime.h>
#include <hip/hip_bf16.h>
#include <math.h>

#define HW 16384          // 128*128
#define IMG 128
#define C_IN 128
#define C_OUT 64
#define NB 8
#define NE 4

// ---------------- K1: pre-fuse 1x1 conv  [B,128,H,W] -> [B,64,H,W] ----------------
__global__ __launch_bounds__(256) void prefuse_kernel(
    const float* __restrict__ x, const float* __restrict__ pre_w,
    const float* __restrict__ pre_b, float* __restrict__ x1) {
  __shared__ float wt[C_IN * C_OUT];  // wt[c*64 + o] = pre_w[o*128 + c]
  int tid = threadIdx.x;
  for (int i = tid; i < C_IN * C_OUT; i += 256) {
    int c = i >> 6, o = i & 63;
    wt[i] = pre_w[o * C_IN + c];
  }

  int p = blockIdx.x * 256 + tid;       // global pixel over [B*HW]
  int b = p >> 14;
  int hw = p & (HW - 1);
  const float* xp = x + (size_t)b * C_IN * HW + hw;

  float acc[C_OUT];
#pragma unroll
  for (int o = 0; o < C_OUT; ++o) acc[o] = pre_b[o];

  __syncthreads();

  for (int c = 0; c < C_IN; c += 2) {
    float xv0 = xp[(size_t)c * HW];
    float xv1 = xp[(size_t)(c + 1) * HW];
    const float4* w0 = (const float4*)(wt + c * C_OUT);
    const float4* w1 = (const float4*)(wt + (c + 1) * C_OUT);
#pragma unroll
    for (int j = 0; j < C_OUT / 4; ++j) {
      float4 a = w0[j];
      acc[4 * j + 0] = fmaf(xv0, a.x, acc[4 * j + 0]);
      acc[4 * j + 1] = fmaf(xv0, a.y, acc[4 * j + 1]);
      acc[4 * j + 2] = fmaf(xv0, a.z, acc[4 * j + 2]);
      acc[4 * j + 3] = fmaf(xv0, a.w, acc[4 * j + 3]);
    }
#pragma unroll
    for (int j = 0; j < C_OUT / 4; ++j) {
      float4 a = w1[j];
      acc[4 * j + 0] = fmaf(xv1, a.x, acc[4 * j + 0]);
      acc[4 * j + 1] = fmaf(xv1, a.y, acc[4 * j + 1]);
      acc[4 * j + 2] = fmaf(xv1, a.z, acc[4 * j + 2]);
      acc[4 * j + 3] = fmaf(xv1, a.w, acc[4 * j + 3]);
    }
  }

  float* op = x1 + (size_t)b * C_OUT * HW + hw;
#pragma unroll
  for (int o = 0; o < C_OUT; ++o) op[(size_t)o * HW] = acc[o];
}

// ---------------- K2: pooled = max(HW) + mean(HW) per (b, c) ----------------
__global__ __launch_bounds__(256) void pool_kernel(const float* __restrict__ x1,
                                                   float* __restrict__ pooled) {
  int bo = blockIdx.x;  // 0..511
  const float4* p = (const float4*)(x1 + (size_t)bo * HW);
  float mx = -INFINITY, sm = 0.f;
  for (int i = threadIdx.x; i < HW / 4; i += 256) {
    float4 v = p[i];
    mx = fmaxf(mx, fmaxf(fmaxf(v.x, v.y), fmaxf(v.z, v.w)));
    sm += (v.x + v.y) + (v.z + v.w);
  }
#pragma unroll
  for (int o = 32; o >= 1; o >>= 1) {
    mx = fmaxf(mx, __shfl_xor(mx, o));
    sm += __shfl_xor(sm, o);
  }
  __shared__ float smx[4], ssm[4];
  int lane = threadIdx.x & 63, wv = threadIdx.x >> 6;
  if (lane == 0) { smx[wv] = mx; ssm[wv] = sm; }
  __syncthreads();
  if (threadIdx.x == 0) {
    float m = fmaxf(fmaxf(smx[0], smx[1]), fmaxf(smx[2], smx[3]));
    float s = (ssm[0] + ssm[1]) + (ssm[2] + ssm[3]);
    pooled[bo] = m + s * (1.0f / HW);
  }
}

// ---------------- K3: gate network -> cof[B][E] ----------------
__global__ __launch_bounds__(64) void gate_kernel(
    const float* __restrict__ pooled, const float* __restrict__ gw0,
    const float* __restrict__ gb0, const float* __restrict__ gw1,
    const float* __restrict__ gb1, float* __restrict__ cof) {
  int b = threadIdx.x;
  if (b >= NB) return;
  float logits[NE], noise[NE];
#pragma unroll
  for (int e = 0; e < NE; ++e) {
    float d0 = gb0[e], d1 = gb1[e];
    for (int k = 0; k < C_OUT; ++k) {
      float pv = pooled[b * C_OUT + k];
      d0 = fmaf(pv, gw0[e * C_OUT + k], d0);
      d1 = fmaf(pv, gw1[e * C_OUT + k], d1);
    }
    logits[e] = d1 > 0.f ? d1 : 0.2f * d1;      // leaky_relu(0.2)
    noise[e] = log1pf(expf(d0));                 // softplus
  }
  float m = 0.25f * (noise[0] + noise[1] + noise[2] + noise[3]);
  float var = 0.f;
#pragma unroll
  for (int e = 0; e < NE; ++e) { float d = noise[e] - m; var += d * d; }
  float sd = sqrtf(var * (1.0f / 3.0f));         // ddof=1
  float scores[NE];
#pragma unroll
  for (int e = 0; e < NE; ++e) scores[e] = logits[e] + (noise[e] - m) / sd;
  // top-2, ties -> lowest index (strict > scan)
  int i0 = 0;
#pragma unroll
  for (int e = 1; e < NE; ++e) if (scores[e] > scores[i0]) i0 = e;
  int i1 = -1;
#pragma unroll
  for (int e = 0; e < NE; ++e)
    if (e != i0 && (i1 < 0 || scores[e] > scores[i1])) i1 = e;
  float mm = fmaxf(logits[i0], logits[i1]);
  float e0 = expf(logits[i0] - mm), e1 = expf(logits[i1] - mm);
  float inv = 1.0f / (e0 + e1);
#pragma unroll
  for (int e = 0; e < NE; ++e) cof[b * NE + e] = 0.f;
  cof[b * NE + i0] = e0 * inv;
  cof[b * NE + i1] = e1 * inv;
}

// ---------------- K4: fused experts: dwconv3x3 -> GELU -> dwconv3x3, gated sum ----
__global__ __launch_bounds__(256) void expert_kernel(
    const float* __restrict__ x1, const float* __restrict__ ew1,
    const float* __restrict__ eb1, const float* __restrict__ ew2,
    const float* __restrict__ eb2, const float* __restrict__ cof,
    float* __restrict__ out) {
  __shared__ float xs[36 * 36];
  __shared__ float hs[34 * 34];
  int tid = threadIdx.x;
  int blk = blockIdx.x;
  int tile = blk & 15;
  int c = (blk >> 4) & 63;
  int b = blk >> 10;
  int ty0 = (tile >> 2) * 32, tx0 = (tile & 3) * 32;

  const float* xp = x1 + ((size_t)b * C_OUT + c) * HW;

  // load 36x36 input tile (halo 2) with zero padding
  for (int i = tid; i < 36 * 36; i += 256) {
    int iy = i / 36, ix = i - iy * 36;
    int gy = ty0 - 2 + iy, gx = tx0 - 2 + ix;
    float v = 0.f;
    if (gy >= 0 && gy < IMG && gx >= 0 && gx < IMG) v = xp[gy * IMG + gx];
    xs[i] = v;
  }

  float acc[4] = {0.f, 0.f, 0.f, 0.f};

  for (int e = 0; e < NE; ++e) {
    float w1[9], w2[9];
#pragma unroll
    for (int k = 0; k < 9; ++k) {
      w1[k] = ew1[((size_t)e * C_OUT + c) * 9 + k];
      w2[k] = ew2[((size_t)e * C_OUT + c) * 9 + k];
    }
    float b1 = eb1[e * C_OUT + c], b2 = eb2[e * C_OUT + c];
    float cf = cof[b * NE + e];

    __syncthreads();  // xs ready (e=0) / hs consumed by previous expert (e>0)

    // h = gelu(dwconv1(x)) on 34x34 (halo 1); h == 0 outside the image
    // (reference zero-pads h for the second SAME conv)
    for (int i = tid; i < 34 * 34; i += 256) {
      int iy = i / 34, ix = i - iy * 34;
      int gy = ty0 - 1 + iy, gx = tx0 - 1 + ix;
      float v = 0.f;
      if (gy >= 0 && gy < IMG && gx >= 0 && gx < IMG) {
        float s = b1;
#pragma unroll
        for (int ky = 0; ky < 3; ++ky)
#pragma unroll
          for (int kx = 0; kx < 3; ++kx)
            s = fmaf(xs[(iy + ky) * 36 + (ix + kx)], w1[ky * 3 + kx], s);
        v = 0.5f * s * (1.0f + erff(s * 0.70710678118654752f));
      }
      hs[i] = v;
    }
    __syncthreads();

    // out_tile += cof * dwconv2(h) on 32x32
#pragma unroll
    for (int k = 0; k < 4; ++k) {
      int idx = tid + k * 256;
      int iy = idx >> 5, ix = idx & 31;
      float s = b2;
#pragma unroll
      for (int ky = 0; ky < 3; ++ky)
#pragma unroll
        for (int kx = 0; kx < 3; ++kx)
          s = fmaf(hs[(iy + ky) * 34 + (ix + kx)], w2[ky * 3 + kx], s);
      acc[k] = fmaf(cf, s, acc[k]);
    }
  }

  float* op = out + ((size_t)b * C_OUT + c) * HW + ty0 * IMG + tx0;
#pragma unroll
  for (int k = 0; k < 4; ++k) {
    int idx = tid + k * 256;
    int iy = idx >> 5, ix = idx & 31;
    op[iy * IMG + ix] = acc[k];
  }
}

extern "C" void kernel_launch(void* const* d_in, const int* in_sizes, int n_in,
                              void* d_out, int out_size, void* d_ws, size_t ws_size,
                              hipStream_t stream) {
  const float* x     = (const float*)d_in[0];
  const float* pre_w = (const float*)d_in[1];
  const float* pre_b = (const float*)d_in[2];
  const float* gw0   = (const float*)d_in[3];
  const float* gb0   = (const float*)d_in[4];
  const float* gw1   = (const float*)d_in[5];
  const float* gb1   = (const float*)d_in[6];
  const float* ew1   = (const float*)d_in[7];
  const float* eb1   = (const float*)d_in[8];
  const float* ew2   = (const float*)d_in[9];
  const float* eb2   = (const float*)d_in[10];
  float* out = (float*)d_out;

  char* ws = (char*)d_ws;
  float* x1     = (float*)ws;                           // 8*64*16384 fp32 = 32 MiB
  float* pooled = (float*)(ws + (size_t)33554432);      // 512 fp32
  float* cof    = pooled + 512;                         // 32 fp32

  prefuse_kernel<<<512, 256, 0, stream>>>(x, pre_w, pre_b, x1);
  pool_kernel<<<512, 256, 0, stream>>>(x1, pooled);
  gate_kernel<<<1, 64, 0, stream>>>(pooled, gw0, gb0, gw1, gb1, cof);
  expert_kernel<<<8192, 256, 0, stream>>>(x1, ew1, eb1, ew2, eb2, cof, out);
}

// Round 3
// 100.897 us; speedup vs baseline: 1.5019x; 1.5019x over previous
//
#include <hip/hip_runtime.h>
#include <hip/hip_bf16.h>
#include <math.h>

#define HW 16384          // 128*128
#define IMG 128
#define C_IN 128
#define C_OUT 64
#define NB 8
#define NE 4

// ---- K1: pre-fuse 1x1 conv + fused partial pooling ----
// block: 4 output-groups x 64 lanes; each thread: 4 pixels x 16 outputs
__global__ __launch_bounds__(256) void prefuse_kernel(
    const float* __restrict__ x, const float* __restrict__ pre_w,
    const float* __restrict__ pre_b, float* __restrict__ x1,
    float* __restrict__ pmax, float* __restrict__ psum) {
  __shared__ float wt[C_IN * C_OUT];  // wt[c*64 + o] = pre_w[o*128 + c]
  int tid = threadIdx.x;
  for (int i = tid; i < C_IN * C_OUT; i += 256) {
    int cc = i >> 6, oo = i & 63;
    wt[i] = pre_w[oo * C_IN + cc];
  }
  int g = tid >> 6, lane = tid & 63;
  int blk = blockIdx.x;               // 512 blocks; 64 per batch
  int b = blk >> 6;
  int hw0 = (blk & 63) * 256 + lane * 4;
  const float* xp = x + (size_t)b * C_IN * HW + hw0;
  int ob = g * 16;

  float4 acc[16];
#pragma unroll
  for (int o = 0; o < 16; ++o) {
    float bv = pre_b[ob + o];
    acc[o] = make_float4(bv, bv, bv, bv);
  }
  __syncthreads();

  for (int c = 0; c < C_IN; ++c) {
    float4 xv = *(const float4*)(xp + (size_t)c * HW);
    float ws[16];
    *(float4*)&ws[0]  = *(const float4*)(wt + c * C_OUT + ob);
    *(float4*)&ws[4]  = *(const float4*)(wt + c * C_OUT + ob + 4);
    *(float4*)&ws[8]  = *(const float4*)(wt + c * C_OUT + ob + 8);
    *(float4*)&ws[12] = *(const float4*)(wt + c * C_OUT + ob + 12);
#pragma unroll
    for (int o = 0; o < 16; ++o) {
      acc[o].x = fmaf(xv.x, ws[o], acc[o].x);
      acc[o].y = fmaf(xv.y, ws[o], acc[o].y);
      acc[o].z = fmaf(xv.z, ws[o], acc[o].z);
      acc[o].w = fmaf(xv.w, ws[o], acc[o].w);
    }
  }

#pragma unroll
  for (int o = 0; o < 16; ++o) {
    *(float4*)(x1 + ((size_t)b * C_OUT + ob + o) * HW + hw0) = acc[o];
    float m = fmaxf(fmaxf(acc[o].x, acc[o].y), fmaxf(acc[o].z, acc[o].w));
    float s = (acc[o].x + acc[o].y) + (acc[o].z + acc[o].w);
#pragma unroll
    for (int d = 32; d >= 1; d >>= 1) {
      m = fmaxf(m, __shfl_xor(m, d));
      s += __shfl_xor(s, d);
    }
    if (lane == 0) {
      int bo = b * C_OUT + ob + o;
      pmax[bo * 64 + (blk & 63)] = m;
      psum[bo * 64 + (blk & 63)] = s;
    }
  }
}

// ---- K2: finish pooling (deterministic fixed-order) ----
__global__ __launch_bounds__(256) void pool2_kernel(
    const float* __restrict__ pmax, const float* __restrict__ psum,
    float* __restrict__ pooled) {
  int bo = blockIdx.x * 256 + threadIdx.x;
  if (bo >= NB * C_OUT) return;
  float m = -INFINITY, s = 0.f;
  for (int k = 0; k < 64; ++k) {
    m = fmaxf(m, pmax[bo * 64 + k]);
    s += psum[bo * 64 + k];
  }
  pooled[bo] = m + s * (1.0f / HW);
}

// ---- K3: gate network -> cof[B][E] ----
__global__ __launch_bounds__(64) void gate_kernel(
    const float* __restrict__ pooled, const float* __restrict__ gw0,
    const float* __restrict__ gb0, const float* __restrict__ gw1,
    const float* __restrict__ gb1, float* __restrict__ cof) {
  int b = threadIdx.x;
  if (b >= NB) return;
  float logits[NE], noise[NE];
#pragma unroll
  for (int e = 0; e < NE; ++e) {
    float d0 = gb0[e], d1 = gb1[e];
    for (int k = 0; k < C_OUT; ++k) {
      float pv = pooled[b * C_OUT + k];
      d0 = fmaf(pv, gw0[e * C_OUT + k], d0);
      d1 = fmaf(pv, gw1[e * C_OUT + k], d1);
    }
    logits[e] = d1 > 0.f ? d1 : 0.2f * d1;
    noise[e] = log1pf(expf(d0));
  }
  float m = 0.25f * (noise[0] + noise[1] + noise[2] + noise[3]);
  float var = 0.f;
#pragma unroll
  for (int e = 0; e < NE; ++e) { float d = noise[e] - m; var += d * d; }
  float sd = sqrtf(var * (1.0f / 3.0f));
  float scores[NE];
#pragma unroll
  for (int e = 0; e < NE; ++e) scores[e] = logits[e] + (noise[e] - m) / sd;
  int i0 = 0;
#pragma unroll
  for (int e = 1; e < NE; ++e) if (scores[e] > scores[i0]) i0 = e;
  int i1 = -1;
#pragma unroll
  for (int e = 0; e < NE; ++e)
    if (e != i0 && (i1 < 0 || scores[e] > scores[i1])) i1 = e;
  float mm = fmaxf(logits[i0], logits[i1]);
  float e0 = expf(logits[i0] - mm), e1 = expf(logits[i1] - mm);
  float inv = 1.0f / (e0 + e1);
#pragma unroll
  for (int e = 0; e < NE; ++e) cof[b * NE + e] = 0.f;
  cof[b * NE + i0] = e0 * inv;
  cof[b * NE + i1] = e1 * inv;
}

// ---- K4: fused experts, vectorized LDS access, cof==0 skip ----
__global__ __launch_bounds__(256) void expert_kernel(
    const float* __restrict__ x1, const float* __restrict__ ew1,
    const float* __restrict__ eb1, const float* __restrict__ ew2,
    const float* __restrict__ eb2, const float* __restrict__ cof,
    float* __restrict__ out) {
  __shared__ float xs[36 * 36 + 8];   // stride 36, +pad for tail overread
  __shared__ float hs[34 * 36 + 8];   // stride 36, cols 0..33 valid
  int tid = threadIdx.x;
  int blk = blockIdx.x;
  int tile = blk & 15;
  int c = (blk >> 4) & 63;
  int b = blk >> 10;
  int ty0 = (tile >> 2) * 32, tx0 = (tile & 3) * 32;
  const float* xp = x1 + ((size_t)b * C_OUT + c) * HW;

  // stage 36x36 x-tile (halo 2), zero outside image
  for (int i = tid; i < 36 * 36; i += 256) {
    int iy = i / 36, ix = i - iy * 36;
    int gy = ty0 - 2 + iy, gx = tx0 - 2 + ix;
    float v = 0.f;
    if ((unsigned)gy < 128u && (unsigned)gx < 128u) v = xp[gy * IMG + gx];
    xs[i] = v;
  }

  int row2 = tid >> 3;          // 0..31
  int oc0 = (tid & 7) * 4;      // 0,4,...,28
  float acc[4] = {0.f, 0.f, 0.f, 0.f};

  for (int e = 0; e < NE; ++e) {
    float cf = cof[b * NE + e];
    if (cf == 0.f) continue;    // uniform per block: exactly 2 active experts
    float w1[9], w2[9];
#pragma unroll
    for (int k = 0; k < 9; ++k) {
      w1[k] = ew1[((size_t)e * C_OUT + c) * 9 + k];
      w2[k] = ew2[((size_t)e * C_OUT + c) * 9 + k];
    }
    float b1 = eb1[e * C_OUT + c], b2 = eb2[e * C_OUT + c];

    __syncthreads();   // xs ready / hs free

    // h = gelu(conv1(x)) over 34 rows x 9 groups of 4 cols
    for (int t = tid; t < 34 * 9; t += 256) {
      int hr = t / 9;
      int g4 = t - hr * 9;
      int hc0 = g4 * 4;
      const float* xr = xs + hr * 36 + hc0;
      float xv[3][6];
#pragma unroll
      for (int dy = 0; dy < 3; ++dy) {
        float4 a = *(const float4*)(xr + dy * 36);
        float2 bb = *(const float2*)(xr + dy * 36 + 4);
        xv[dy][0] = a.x; xv[dy][1] = a.y; xv[dy][2] = a.z; xv[dy][3] = a.w;
        xv[dy][4] = bb.x; xv[dy][5] = bb.y;
      }
      int gy = ty0 - 1 + hr;
      int gx0 = tx0 - 1 + hc0;
      float4 hv;
      float* hvp = (float*)&hv;
#pragma unroll
      for (int j = 0; j < 4; ++j) {
        float s = b1;
#pragma unroll
        for (int dy = 0; dy < 3; ++dy)
#pragma unroll
          for (int dx = 0; dx < 3; ++dx)
            s = fmaf(xv[dy][j + dx], w1[dy * 3 + dx], s);
        // gelu(s) = 0.5s + k*s^2*(1 - u/6 + u^2/40 - u^3/336), u=s^2, |s|<~0.3
        float u = s * s;
        float tp = 1.f - u * (0.16666667f - u * (0.025f - u * 0.0029761905f));
        float h = s * fmaf(0.3989422804f * s, tp, 0.5f);
        bool ok = ((unsigned)gy < 128u) && ((unsigned)(gx0 + j) < 128u);
        hvp[j] = ok ? h : 0.f;
      }
      *(float4*)(hs + hr * 36 + hc0) = hv;
    }
    __syncthreads();   // hs ready

    // out += cof * conv2(h): 4 outputs per thread (row2, oc0..oc0+3)
    const float* hp = hs + row2 * 36 + oc0;
    float s0 = b2, s1 = b2, s2 = b2, s3 = b2;
#pragma unroll
    for (int dy = 0; dy < 3; ++dy) {
      float4 a = *(const float4*)(hp + dy * 36);
      float2 bb = *(const float2*)(hp + dy * 36 + 4);
      float h0 = a.x, h1 = a.y, h2 = a.z, h3 = a.w, h4 = bb.x, h5 = bb.y;
      float wA = w2[dy * 3], wB = w2[dy * 3 + 1], wC = w2[dy * 3 + 2];
      s0 = fmaf(h0, wA, fmaf(h1, wB, fmaf(h2, wC, s0)));
      s1 = fmaf(h1, wA, fmaf(h2, wB, fmaf(h3, wC, s1)));
      s2 = fmaf(h2, wA, fmaf(h3, wB, fmaf(h4, wC, s2)));
      s3 = fmaf(h3, wA, fmaf(h4, wB, fmaf(h5, wC, s3)));
    }
    acc[0] = fmaf(cf, s0, acc[0]);
    acc[1] = fmaf(cf, s1, acc[1]);
    acc[2] = fmaf(cf, s2, acc[2]);
    acc[3] = fmaf(cf, s3, acc[3]);
  }

  float4 o4 = make_float4(acc[0], acc[1], acc[2], acc[3]);
  *(float4*)(out + ((size_t)b * C_OUT + c) * HW + (ty0 + row2) * IMG + tx0 + oc0) = o4;
}

extern "C" void kernel_launch(void* const* d_in, const int* in_sizes, int n_in,
                              void* d_out, int out_size, void* d_ws, size_t ws_size,
                              hipStream_t stream) {
  const float* x     = (const float*)d_in[0];
  const float* pre_w = (const float*)d_in[1];
  const float* pre_b = (const float*)d_in[2];
  const float* gw0   = (const float*)d_in[3];
  const float* gb0   = (const float*)d_in[4];
  const float* gw1   = (const float*)d_in[5];
  const float* gb1   = (const float*)d_in[6];
  const float* ew1   = (const float*)d_in[7];
  const float* eb1   = (const float*)d_in[8];
  const float* ew2   = (const float*)d_in[9];
  const float* eb2   = (const float*)d_in[10];
  float* out = (float*)d_out;

  char* ws = (char*)d_ws;
  float* x1     = (float*)ws;                                  // 32 MiB
  float* pmax   = (float*)(ws + 33554432);                     // 512*64 fp32
  float* psum   = (float*)(ws + 33554432 + 131072);            // 512*64 fp32
  float* pooled = (float*)(ws + 33554432 + 262144);            // 512 fp32
  float* cof    = (float*)(ws + 33554432 + 262144 + 2048);     // 32 fp32

  prefuse_kernel<<<512, 256, 0, stream>>>(x, pre_w, pre_b, x1, pmax, psum);
  pool2_kernel<<<2, 256, 0, stream>>>(pmax, psum, pooled);
  gate_kernel<<<1, 64, 0, stream>>>(pooled, gw0, gb0, gw1, gb1, cof);
  expert_kernel<<<8192, 256, 0, stream>>>(x1, ew1, eb1, ew2, eb2, cof, out);
}

// Round 4
// 91.094 us; speedup vs baseline: 1.6635x; 1.1076x over previous
//
#include <hip/hip_runtime.h>
#include <hip/hip_bf16.h>
#include <math.h>

#define HW 16384          // 128*128
#define IMG 128
#define C_IN 128
#define C_OUT 64
#define NB 8
#define NE 4

// ---- K1: pre-fuse 1x1 conv + fused partial pooling ----
// 512 threads = 8 waves; wave g handles outputs [8g, 8g+8); each thread 8 pixels.
// grid 256 = 1 block/CU; block covers 512 pixels.
__global__ __launch_bounds__(512) void prefuse_kernel(
    const float* __restrict__ x, const float* __restrict__ pre_w,
    const float* __restrict__ pre_b, float* __restrict__ x1,
    float* __restrict__ pmax, float* __restrict__ psum) {
  __shared__ float wt[C_IN * C_OUT];  // wt[c*64 + o] = pre_w[o*128 + c]
  int tid = threadIdx.x;
  for (int i = tid; i < C_IN * C_OUT; i += 512) {
    int cc = i >> 6, oo = i & 63;
    wt[i] = pre_w[oo * C_IN + cc];    // strided read, conflict-free LDS write
  }
  int g = tid >> 6, lane = tid & 63;
  int blk = blockIdx.x;               // 256 blocks; 32 per batch
  int b = blk >> 5;
  int part = blk & 31;
  int hw0 = part * 512 + lane * 4;    // first float4; second at +256
  const float* xp = x + (size_t)b * C_IN * HW + hw0;
  int ob = g * 8;

  float4 acc[16];                     // [o][2 float4] : 8 outputs x 8 px
#pragma unroll
  for (int o = 0; o < 8; ++o) {
    float bv = pre_b[ob + o];
    acc[2 * o]     = make_float4(bv, bv, bv, bv);
    acc[2 * o + 1] = make_float4(bv, bv, bv, bv);
  }
  __syncthreads();

  float4 pA0 = *(const float4*)(xp);
  float4 pA1 = *(const float4*)(xp + 256);

  for (int c = 0; c < C_IN; ++c) {
    float4 pB0, pB1;
    if (c + 1 < C_IN) {
      pB0 = *(const float4*)(xp + (size_t)(c + 1) * HW);
      pB1 = *(const float4*)(xp + (size_t)(c + 1) * HW + 256);
    }
    float4 w0 = *(const float4*)(wt + c * C_OUT + ob);      // wave-uniform broadcast
    float4 w1 = *(const float4*)(wt + c * C_OUT + ob + 4);
    const float* wp = (const float*)&w0;
#pragma unroll
    for (int o = 0; o < 4; ++o) {
      float wv = wp[o];
      acc[2*o].x   = fmaf(pA0.x, wv, acc[2*o].x);
      acc[2*o].y   = fmaf(pA0.y, wv, acc[2*o].y);
      acc[2*o].z   = fmaf(pA0.z, wv, acc[2*o].z);
      acc[2*o].w   = fmaf(pA0.w, wv, acc[2*o].w);
      acc[2*o+1].x = fmaf(pA1.x, wv, acc[2*o+1].x);
      acc[2*o+1].y = fmaf(pA1.y, wv, acc[2*o+1].y);
      acc[2*o+1].z = fmaf(pA1.z, wv, acc[2*o+1].z);
      acc[2*o+1].w = fmaf(pA1.w, wv, acc[2*o+1].w);
    }
    const float* wq = (const float*)&w1;
#pragma unroll
    for (int o = 0; o < 4; ++o) {
      float wv = wq[o];
      int oo = o + 4;
      acc[2*oo].x   = fmaf(pA0.x, wv, acc[2*oo].x);
      acc[2*oo].y   = fmaf(pA0.y, wv, acc[2*oo].y);
      acc[2*oo].z   = fmaf(pA0.z, wv, acc[2*oo].z);
      acc[2*oo].w   = fmaf(pA0.w, wv, acc[2*oo].w);
      acc[2*oo+1].x = fmaf(pA1.x, wv, acc[2*oo+1].x);
      acc[2*oo+1].y = fmaf(pA1.y, wv, acc[2*oo+1].y);
      acc[2*oo+1].z = fmaf(pA1.z, wv, acc[2*oo+1].z);
      acc[2*oo+1].w = fmaf(pA1.w, wv, acc[2*oo+1].w);
    }
    pA0 = pB0;
    pA1 = pB1;
  }

#pragma unroll
  for (int o = 0; o < 8; ++o) {
    float4 a0 = acc[2 * o], a1 = acc[2 * o + 1];
    float* op = x1 + ((size_t)b * C_OUT + ob + o) * HW + hw0;
    *(float4*)op = a0;
    *(float4*)(op + 256) = a1;
    float m = fmaxf(fmaxf(fmaxf(a0.x, a0.y), fmaxf(a0.z, a0.w)),
                    fmaxf(fmaxf(a1.x, a1.y), fmaxf(a1.z, a1.w)));
    float s = ((a0.x + a0.y) + (a0.z + a0.w)) + ((a1.x + a1.y) + (a1.z + a1.w));
#pragma unroll
    for (int d = 32; d >= 1; d >>= 1) {
      m = fmaxf(m, __shfl_xor(m, d));
      s += __shfl_xor(s, d);
    }
    if (lane == 0) {
      int bo = b * C_OUT + ob + o;
      pmax[bo * 32 + part] = m;
      psum[bo * 32 + part] = s;
    }
  }
}

// ---- K2: finish pooling + gate network -> cof[B][E] (one small block) ----
__global__ __launch_bounds__(512) void pool_gate_kernel(
    const float* __restrict__ pmax, const float* __restrict__ psum,
    const float* __restrict__ gw0, const float* __restrict__ gb0,
    const float* __restrict__ gw1, const float* __restrict__ gb1,
    float* __restrict__ cof) {
  __shared__ float pooled[NB * C_OUT];
  int bo = threadIdx.x;  // 0..511
  float m = -INFINITY, s = 0.f;
  for (int k = 0; k < 32; ++k) {
    m = fmaxf(m, pmax[bo * 32 + k]);
    s += psum[bo * 32 + k];
  }
  pooled[bo] = m + s * (1.0f / HW);
  __syncthreads();

  int b = threadIdx.x;
  if (b >= NB) return;
  float logits[NE], noise[NE];
#pragma unroll
  for (int e = 0; e < NE; ++e) {
    float d0 = gb0[e], d1 = gb1[e];
    for (int k = 0; k < C_OUT; ++k) {
      float pv = pooled[b * C_OUT + k];
      d0 = fmaf(pv, gw0[e * C_OUT + k], d0);
      d1 = fmaf(pv, gw1[e * C_OUT + k], d1);
    }
    logits[e] = d1 > 0.f ? d1 : 0.2f * d1;
    noise[e] = log1pf(expf(d0));
  }
  float mn = 0.25f * (noise[0] + noise[1] + noise[2] + noise[3]);
  float var = 0.f;
#pragma unroll
  for (int e = 0; e < NE; ++e) { float d = noise[e] - mn; var += d * d; }
  float sd = sqrtf(var * (1.0f / 3.0f));
  float scores[NE];
#pragma unroll
  for (int e = 0; e < NE; ++e) scores[e] = logits[e] + (noise[e] - mn) / sd;
  int i0 = 0;
#pragma unroll
  for (int e = 1; e < NE; ++e) if (scores[e] > scores[i0]) i0 = e;
  int i1 = -1;
#pragma unroll
  for (int e = 0; e < NE; ++e)
    if (e != i0 && (i1 < 0 || scores[e] > scores[i1])) i1 = e;
  float mm = fmaxf(logits[i0], logits[i1]);
  float e0 = expf(logits[i0] - mm), e1 = expf(logits[i1] - mm);
  float inv = 1.0f / (e0 + e1);
#pragma unroll
  for (int e = 0; e < NE; ++e) cof[b * NE + e] = 0.f;
  cof[b * NE + i0] = e0 * inv;
  cof[b * NE + i1] = e1 * inv;
}

// ---- K3: fused experts, vectorized LDS access, cof==0 skip ----
__global__ __launch_bounds__(256) void expert_kernel(
    const float* __restrict__ x1, const float* __restrict__ ew1,
    const float* __restrict__ eb1, const float* __restrict__ ew2,
    const float* __restrict__ eb2, const float* __restrict__ cof,
    float* __restrict__ out) {
  __shared__ float xs[36 * 36 + 8];   // stride 36, +pad for tail overread
  __shared__ float hs[34 * 36 + 8];   // stride 36, cols 0..33 valid
  int tid = threadIdx.x;
  int blk = blockIdx.x;
  int tile = blk & 15;
  int c = (blk >> 4) & 63;
  int b = blk >> 10;
  int ty0 = (tile >> 2) * 32, tx0 = (tile & 3) * 32;
  const float* xp = x1 + ((size_t)b * C_OUT + c) * HW;

  // stage 36x36 x-tile (halo 2), zero outside image
  for (int i = tid; i < 36 * 36; i += 256) {
    int iy = i / 36, ix = i - iy * 36;
    int gy = ty0 - 2 + iy, gx = tx0 - 2 + ix;
    float v = 0.f;
    if ((unsigned)gy < 128u && (unsigned)gx < 128u) v = xp[gy * IMG + gx];
    xs[i] = v;
  }

  int row2 = tid >> 3;          // 0..31
  int oc0 = (tid & 7) * 4;      // 0,4,...,28
  float acc[4] = {0.f, 0.f, 0.f, 0.f};

  for (int e = 0; e < NE; ++e) {
    float cf = cof[b * NE + e];
    if (cf == 0.f) continue;    // uniform per block: exactly 2 active experts
    float w1[9], w2[9];
#pragma unroll
    for (int k = 0; k < 9; ++k) {
      w1[k] = ew1[((size_t)e * C_OUT + c) * 9 + k];
      w2[k] = ew2[((size_t)e * C_OUT + c) * 9 + k];
    }
    float b1 = eb1[e * C_OUT + c], b2 = eb2[e * C_OUT + c];

    __syncthreads();   // xs ready / hs free

    // h = gelu(conv1(x)) over 34 rows x 9 groups of 4 cols
    for (int t = tid; t < 34 * 9; t += 256) {
      int hr = t / 9;
      int g4 = t - hr * 9;
      int hc0 = g4 * 4;
      const float* xr = xs + hr * 36 + hc0;
      float xv[3][6];
#pragma unroll
      for (int dy = 0; dy < 3; ++dy) {
        float4 a = *(const float4*)(xr + dy * 36);
        float2 bb = *(const float2*)(xr + dy * 36 + 4);
        xv[dy][0] = a.x; xv[dy][1] = a.y; xv[dy][2] = a.z; xv[dy][3] = a.w;
        xv[dy][4] = bb.x; xv[dy][5] = bb.y;
      }
      int gy = ty0 - 1 + hr;
      int gx0 = tx0 - 1 + hc0;
      float4 hv;
      float* hvp = (float*)&hv;
#pragma unroll
      for (int j = 0; j < 4; ++j) {
        float s = b1;
#pragma unroll
        for (int dy = 0; dy < 3; ++dy)
#pragma unroll
          for (int dx = 0; dx < 3; ++dx)
            s = fmaf(xv[dy][j + dx], w1[dy * 3 + dx], s);
        // gelu(s) = 0.5s + k*s^2*(1 - u/6 + u^2/40 - u^3/336), u=s^2, |s|<~0.3
        float u = s * s;
        float tp = 1.f - u * (0.16666667f - u * (0.025f - u * 0.0029761905f));
        float h = s * fmaf(0.3989422804f * s, tp, 0.5f);
        bool ok = ((unsigned)gy < 128u) && ((unsigned)(gx0 + j) < 128u);
        hvp[j] = ok ? h : 0.f;
      }
      *(float4*)(hs + hr * 36 + hc0) = hv;
    }
    __syncthreads();   // hs ready

    // out += cof * conv2(h): 4 outputs per thread (row2, oc0..oc0+3)
    const float* hp = hs + row2 * 36 + oc0;
    float s0 = b2, s1 = b2, s2 = b2, s3 = b2;
#pragma unroll
    for (int dy = 0; dy < 3; ++dy) {
      float4 a = *(const float4*)(hp + dy * 36);
      float2 bb = *(const float2*)(hp + dy * 36 + 4);
      float h0 = a.x, h1 = a.y, h2 = a.z, h3 = a.w, h4 = bb.x, h5 = bb.y;
      float wA = w2[dy * 3], wB = w2[dy * 3 + 1], wC = w2[dy * 3 + 2];
      s0 = fmaf(h0, wA, fmaf(h1, wB, fmaf(h2, wC, s0)));
      s1 = fmaf(h1, wA, fmaf(h2, wB, fmaf(h3, wC, s1)));
      s2 = fmaf(h2, wA, fmaf(h3, wB, fmaf(h4, wC, s2)));
      s3 = fmaf(h3, wA, fmaf(h4, wB, fmaf(h5, wC, s3)));
    }
    acc[0] = fmaf(cf, s0, acc[0]);
    acc[1] = fmaf(cf, s1, acc[1]);
    acc[2] = fmaf(cf, s2, acc[2]);
    acc[3] = fmaf(cf, s3, acc[3]);
  }

  float4 o4 = make_float4(acc[0], acc[1], acc[2], acc[3]);
  *(float4*)(out + ((size_t)b * C_OUT + c) * HW + (ty0 + row2) * IMG + tx0 + oc0) = o4;
}

extern "C" void kernel_launch(void* const* d_in, const int* in_sizes, int n_in,
                              void* d_out, int out_size, void* d_ws, size_t ws_size,
                              hipStream_t stream) {
  const float* x     = (const float*)d_in[0];
  const float* pre_w = (const float*)d_in[1];
  const float* pre_b = (const float*)d_in[2];
  const float* gw0   = (const float*)d_in[3];
  const float* gb0   = (const float*)d_in[4];
  const float* gw1   = (const float*)d_in[5];
  const float* gb1   = (const float*)d_in[6];
  const float* ew1   = (const float*)d_in[7];
  const float* eb1   = (const float*)d_in[8];
  const float* ew2   = (const float*)d_in[9];
  const float* eb2   = (const float*)d_in[10];
  float* out = (float*)d_out;

  char* ws = (char*)d_ws;
  float* x1   = (float*)ws;                            // 32 MiB
  float* pmax = (float*)(ws + 33554432);               // 512*32 fp32 = 64 KiB
  float* psum = (float*)(ws + 33554432 + 65536);       // 512*32 fp32
  float* cof  = (float*)(ws + 33554432 + 131072);      // 32 fp32

  prefuse_kernel<<<256, 512, 0, stream>>>(x, pre_w, pre_b, x1, pmax, psum);
  pool_gate_kernel<<<1, 512, 0, stream>>>(pmax, psum, gw0, gb0, gw1, gb1, cof);
  expert_kernel<<<8192, 256, 0, stream>>>(x1, ew1, eb1, ew2, eb2, cof, out);
}